// Round 1
// baseline (423.394 us; speedup 1.0000x reference)
//
#include <hip/hip_runtime.h>
#include <stdint.h>

// BraidCrossing: scale = mean(softmax(.), axis=-1) == 1/6 exactly => W1/b1/W2/b2/gelu dead.
// out_t = LN(LN(x_t + P_{t-1}/6) + P_{t+1}/6), P = x @ Wp^T + bp, one-sided at t=0, T-1.
// R4: GEMM -> 256x256 tile, BK=64, 8 waves, 8-phase schedule with counted vmcnt
// (T3+T4), setprio around MFMA clusters (T5), XCD-bijective swizzle (T1), chunk-XOR
// LDS swizzle carried from R3 (measured 0 bank conflicts). LN -> wave-per-row (no
// __syncthreads, shuffle-only reduce).

#define B_DIM 8
#define T_DIM 2048
#define D_DIM 2048
#define M_DIM (B_DIM * T_DIM)   // 16384
#define N_DIM D_DIM             // 2048
#define K_DIM D_DIM             // 2048
#define NT (K_DIM / 64)         // 32 K-tiles

typedef __attribute__((ext_vector_type(8))) short short8;   // 8 bf16 in 4 VGPRs
typedef __attribute__((ext_vector_type(4))) float f32x4;

__device__ inline unsigned short f2bf(float f) {
    unsigned u = __float_as_uint(f);
    u += 0x7fffu + ((u >> 16) & 1u);   // RTNE
    return (unsigned short)(u >> 16);
}
__device__ inline float bf2f(unsigned u16) {
    return __uint_as_float(u16 << 16);
}
__device__ inline void unpack8(uint4 u, float* f) {
    f[0] = bf2f(u.x & 0xffffu); f[1] = bf2f(u.x >> 16);
    f[2] = bf2f(u.y & 0xffffu); f[3] = bf2f(u.y >> 16);
    f[4] = bf2f(u.z & 0xffffu); f[5] = bf2f(u.z >> 16);
    f[6] = bf2f(u.w & 0xffffu); f[7] = bf2f(u.w >> 16);
}
__device__ inline void async_ld16(const void* g, void* l) {
    __builtin_amdgcn_global_load_lds(
        (__attribute__((address_space(1))) void*)(g),
        (__attribute__((address_space(3))) void*)(l),
        16, 0, 0);
}

#define VMCNT(n) asm volatile("s_waitcnt vmcnt(" #n ")" ::: "memory")
#define LGKM0    asm volatile("s_waitcnt lgkmcnt(0)" ::: "memory")

// ---------------- cast f32 -> bf16 (x and Wp in one launch) ----------------
__global__ void cast_f32_bf16(const float* __restrict__ x, unsigned short* __restrict__ Xb,
                              const float* __restrict__ Wp, unsigned short* __restrict__ Wb,
                              int nx4, int ntot4) {
    int i = blockIdx.x * blockDim.x + threadIdx.x;
    if (i >= ntot4) return;
    const float* src; unsigned short* dst; int j;
    if (i < nx4) { src = x; dst = Xb; j = i; }
    else         { src = Wp; dst = Wb; j = i - nx4; }
    float4 f = ((const float4*)src)[j];
    ushort4 o;
    o.x = f2bf(f.x); o.y = f2bf(f.y); o.z = f2bf(f.z); o.w = f2bf(f.w);
    ((ushort4*)dst)[j] = o;
}

// ---------------- GEMM: P = Xb(MxK) @ Wb(NxK)^T + bp, bf16 in, bf16 out ----------------
// 256x256 tile, BK=64, 512 threads (8 waves, 2Mx4N), each wave 128x64 output.
// LDS: [2 dbuf][256 rows][64 cols] bf16 per matrix = 128 KiB total.
// Row layout 128 B (8 x 16B chunks); read-side swizzle phys_chunk = logical ^ (row&7),
// staged by pre-swizzling the per-lane GLOBAL source col; LDS dest stays linear
// (global_load_lds is wave-uniform-base + lane*16).
// Per K-tile: 4 phases. Issue order for tile t+1 (into buf^1): B0,B1 | B2,B3 | A0,A2 | A1,A3.
// Phase needs: p0 reads all B + A rows [0,32) (granules A0/A2); p2 reads A rows [64,96)
// (granules A1/A3)  =>  waits: vmcnt(4) end of p1 (drains A1,A3 of tile t),
// vmcnt(2) end of p3 (drains B0..B3,A0,A2 of tile t+1). Never 0 in the main loop.

template <int PP>
__device__ __attribute__((always_inline)) inline
void mfma16(f32x4 (&acc)[8][4], const short8 (&a)[2][2], const short8 (&b)[4][2]) {
#pragma unroll
    for (int kk = 0; kk < 2; ++kk)
#pragma unroll
        for (int i = 0; i < 2; ++i)
#pragma unroll
            for (int j = 0; j < 4; ++j)
                acc[PP * 2 + i][j] = __builtin_amdgcn_mfma_f32_16x16x32_bf16(
                    a[i][kk], b[j][kk], acc[PP * 2 + i][j], 0, 0, 0);
}

__global__ __launch_bounds__(512, 2)
void gemm_bt(const unsigned short* __restrict__ Xb,
             const unsigned short* __restrict__ Wb,
             const float* __restrict__ bp,
             unsigned short* __restrict__ P)
{
    __shared__ unsigned short As[2][256 * 64];   // 64 KB
    __shared__ unsigned short Bs[2][256 * 64];   // 64 KB

    const int tid  = threadIdx.x;
    const int lane = tid & 63;
    const int wave = tid >> 6;
    const int wm = wave >> 2;            // 0..1  (M half)
    const int wn = wave & 3;             // 0..3  (N quarter)
    const int fr = lane & 15;            // fragment row
    const int lq = lane >> 4;            // k-chunk within 32-wide step
    const int xa = fr & 7;               // read-side XOR (row&7 == fr&7 for all frag rows)

    // XCD-bijective swizzle: nwg=512, 512%8==0. Each XCD gets an 8x8 supertile.
    const int bid = blockIdx.x;
    const int swz = (bid & 7) * 64 + (bid >> 3);
    const int m0 = (swz >> 3) * 256;     // 64 M-tiles
    const int n0 = (swz & 7) * 256;      // 8 N-tiles

    // staging map: granule = 64 rows x 64 cols (8 KB) = one global_load_lds per granule.
    // thread tid stages 16 B: row rr = tid>>3, phys chunk cc = tid&7,
    // global logical chunk = cc ^ (rr&7)  (inverse == same involution as read side).
    const int rr = tid >> 3;
    const int cc = tid & 7;
    const int lc8 = (cc ^ (rr & 7)) * 8;
    const unsigned short* Ag = Xb + (size_t)(m0 + rr) * K_DIM + lc8;
    const unsigned short* Bg = Wb + (size_t)(n0 + rr) * K_DIM + lc8;

#define STAGE_A(buf, g, k0) async_ld16(Ag + (size_t)(g) * 64 * K_DIM + (k0), \
                                       &As[buf][((g) * 64 + rr) * 64 + cc * 8])
#define STAGE_B(buf, g, k0) async_ld16(Bg + (size_t)(g) * 64 * K_DIM + (k0), \
                                       &Bs[buf][((g) * 64 + rr) * 64 + cc * 8])
#define LDA(dst, buf, p, i, kk) dst = *(const short8*)&As[buf][ \
        (wm * 128 + (p) * 32 + (i) * 16 + fr) * 64 + ((((kk) * 4 + lq) ^ xa) * 8)]
#define LDB(dst, buf, j, kk)    dst = *(const short8*)&Bs[buf][ \
        (wn * 64 + (j) * 16 + fr) * 64 + ((((kk) * 4 + lq) ^ xa) * 8)]

    f32x4 acc[8][4];
#pragma unroll
    for (int i = 0; i < 8; ++i)
#pragma unroll
        for (int j = 0; j < 4; ++j) acc[i][j] = (f32x4){0.f, 0.f, 0.f, 0.f};

    // prologue: tile 0 -> buf 0, deferred-last order; leave A1,A3 in flight.
    STAGE_B(0, 0, 0); STAGE_B(0, 1, 0); STAGE_B(0, 2, 0); STAGE_B(0, 3, 0);
    STAGE_A(0, 0, 0); STAGE_A(0, 2, 0); STAGE_A(0, 1, 0); STAGE_A(0, 3, 0);
    VMCNT(2);
    __builtin_amdgcn_s_barrier();

    short8 a[2][2], b[4][2];
    for (int t = 0; t < NT - 1; ++t) {
        const int cur = t & 1, nxt = cur ^ 1;
        const int kn = (t + 1) * 64;

        // ---- phase 0: all B frags + A rows [0,32); issue B0,B1(t+1) ----
        LDB(b[0][0], cur, 0, 0); LDB(b[0][1], cur, 0, 1);
        LDB(b[1][0], cur, 1, 0); LDB(b[1][1], cur, 1, 1);
        LDB(b[2][0], cur, 2, 0); LDB(b[2][1], cur, 2, 1);
        LDB(b[3][0], cur, 3, 0); LDB(b[3][1], cur, 3, 1);
        LDA(a[0][0], cur, 0, 0, 0); LDA(a[0][1], cur, 0, 0, 1);
        LDA(a[1][0], cur, 0, 1, 0); LDA(a[1][1], cur, 0, 1, 1);
        STAGE_B(nxt, 0, kn); STAGE_B(nxt, 1, kn);
        __builtin_amdgcn_s_barrier();
        LGKM0; __builtin_amdgcn_sched_barrier(0);
        __builtin_amdgcn_s_setprio(1);
        mfma16<0>(acc, a, b);
        __builtin_amdgcn_s_setprio(0);
        __builtin_amdgcn_s_barrier();

        // ---- phase 1: A rows [32,64); issue B2,B3(t+1); drain A1,A3(t) ----
        LDA(a[0][0], cur, 1, 0, 0); LDA(a[0][1], cur, 1, 0, 1);
        LDA(a[1][0], cur, 1, 1, 0); LDA(a[1][1], cur, 1, 1, 1);
        STAGE_B(nxt, 2, kn); STAGE_B(nxt, 3, kn);
        __builtin_amdgcn_s_barrier();
        LGKM0; __builtin_amdgcn_sched_barrier(0);
        __builtin_amdgcn_s_setprio(1);
        mfma16<1>(acc, a, b);
        __builtin_amdgcn_s_setprio(0);
        VMCNT(4);
        __builtin_amdgcn_s_barrier();

        // ---- phase 2: A rows [64,96); issue A0,A2(t+1) ----
        LDA(a[0][0], cur, 2, 0, 0); LDA(a[0][1], cur, 2, 0, 1);
        LDA(a[1][0], cur, 2, 1, 0); LDA(a[1][1], cur, 2, 1, 1);
        STAGE_A(nxt, 0, kn); STAGE_A(nxt, 2, kn);
        __builtin_amdgcn_s_barrier();
        LGKM0; __builtin_amdgcn_sched_barrier(0);
        __builtin_amdgcn_s_setprio(1);
        mfma16<2>(acc, a, b);
        __builtin_amdgcn_s_setprio(0);
        __builtin_amdgcn_s_barrier();

        // ---- phase 3: A rows [96,128); issue A1,A3(t+1); drain all but A1,A3(t+1) ----
        LDA(a[0][0], cur, 3, 0, 0); LDA(a[0][1], cur, 3, 0, 1);
        LDA(a[1][0], cur, 3, 1, 0); LDA(a[1][1], cur, 3, 1, 1);
        STAGE_A(nxt, 1, kn); STAGE_A(nxt, 3, kn);
        __builtin_amdgcn_s_barrier();
        LGKM0; __builtin_amdgcn_sched_barrier(0);
        __builtin_amdgcn_s_setprio(1);
        mfma16<3>(acc, a, b);
        __builtin_amdgcn_s_setprio(0);
        VMCNT(2);
        __builtin_amdgcn_s_barrier();
    }

    // ---- tail tile NT-1 (buf 1), no further issues ----
    {
        const int cur = (NT - 1) & 1;
        LDB(b[0][0], cur, 0, 0); LDB(b[0][1], cur, 0, 1);
        LDB(b[1][0], cur, 1, 0); LDB(b[1][1], cur, 1, 1);
        LDB(b[2][0], cur, 2, 0); LDB(b[2][1], cur, 2, 1);
        LDB(b[3][0], cur, 3, 0); LDB(b[3][1], cur, 3, 1);
        LDA(a[0][0], cur, 0, 0, 0); LDA(a[0][1], cur, 0, 0, 1);
        LDA(a[1][0], cur, 0, 1, 0); LDA(a[1][1], cur, 0, 1, 1);
        __builtin_amdgcn_s_barrier();
        LGKM0; __builtin_amdgcn_sched_barrier(0);
        __builtin_amdgcn_s_setprio(1);
        mfma16<0>(acc, a, b);
        __builtin_amdgcn_s_setprio(0);
        __builtin_amdgcn_s_barrier();

        LDA(a[0][0], cur, 1, 0, 0); LDA(a[0][1], cur, 1, 0, 1);
        LDA(a[1][0], cur, 1, 1, 0); LDA(a[1][1], cur, 1, 1, 1);
        __builtin_amdgcn_s_barrier();
        LGKM0; __builtin_amdgcn_sched_barrier(0);
        __builtin_amdgcn_s_setprio(1);
        mfma16<1>(acc, a, b);
        __builtin_amdgcn_s_setprio(0);
        VMCNT(0);                       // drain A1,A3 of the last tile
        __builtin_amdgcn_s_barrier();

        LDA(a[0][0], cur, 2, 0, 0); LDA(a[0][1], cur, 2, 0, 1);
        LDA(a[1][0], cur, 2, 1, 0); LDA(a[1][1], cur, 2, 1, 1);
        __builtin_amdgcn_s_barrier();
        LGKM0; __builtin_amdgcn_sched_barrier(0);
        __builtin_amdgcn_s_setprio(1);
        mfma16<2>(acc, a, b);
        __builtin_amdgcn_s_setprio(0);
        __builtin_amdgcn_s_barrier();

        LDA(a[0][0], cur, 3, 0, 0); LDA(a[0][1], cur, 3, 0, 1);
        LDA(a[1][0], cur, 3, 1, 0); LDA(a[1][1], cur, 3, 1, 1);
        LGKM0; __builtin_amdgcn_sched_barrier(0);
        __builtin_amdgcn_s_setprio(1);
        mfma16<3>(acc, a, b);
        __builtin_amdgcn_s_setprio(0);
    }

    // epilogue: C/D layout col=lane&15, row=(lane>>4)*4+reg  [m89/m91-verified]
    const int crow = (lane >> 4) * 4;
    const int ccol = lane & 15;
#pragma unroll
    for (int j = 0; j < 4; ++j) {
        const int col = n0 + wn * 64 + 16 * j + ccol;
        const float bpv = bp[col];
#pragma unroll
        for (int mi = 0; mi < 8; ++mi) {
            size_t base = (size_t)(m0 + wm * 128 + 16 * mi + crow) * N_DIM + col;
#pragma unroll
            for (int r = 0; r < 4; ++r)
                P[base + (size_t)r * N_DIM] = f2bf(acc[mi][j][r] + bpv);
        }
    }
#undef STAGE_A
#undef STAGE_B
#undef LDA
#undef LDB
}

// ---------------- fused double-LayerNorm: one wave per row ----------------
__device__ __attribute__((always_inline)) inline
void ln_wave(float* v, const float* __restrict__ gamma, const float* __restrict__ beta,
             int lane) {
    float s = 0.f, q = 0.f;
#pragma unroll
    for (int i = 0; i < 32; ++i) { s += v[i]; q += v[i] * v[i]; }
#pragma unroll
    for (int off = 32; off; off >>= 1) {
        s += __shfl_xor(s, off);
        q += __shfl_xor(q, off);
    }
    const float invD = 1.0f / (float)D_DIM;
    const float mu = s * invD;
    const float rs = rsqrtf(q * invD - mu * mu + 1e-5f);
    const float4* g4 = (const float4*)gamma;
    const float4* b4 = (const float4*)beta;
#pragma unroll
    for (int c = 0; c < 4; ++c) {
        const int e = (c * 64 + lane) * 2;
        float4 g0 = g4[e], g1 = g4[e + 1];
        float4 b0 = b4[e], b1 = b4[e + 1];
        v[c*8+0] = (v[c*8+0] - mu) * rs * g0.x + b0.x;
        v[c*8+1] = (v[c*8+1] - mu) * rs * g0.y + b0.y;
        v[c*8+2] = (v[c*8+2] - mu) * rs * g0.z + b0.z;
        v[c*8+3] = (v[c*8+3] - mu) * rs * g0.w + b0.w;
        v[c*8+4] = (v[c*8+4] - mu) * rs * g1.x + b1.x;
        v[c*8+5] = (v[c*8+5] - mu) * rs * g1.y + b1.y;
        v[c*8+6] = (v[c*8+6] - mu) * rs * g1.z + b1.z;
        v[c*8+7] = (v[c*8+7] - mu) * rs * g1.w + b1.w;
    }
}

__global__ __launch_bounds__(256)
void ln_kernel(const unsigned short* __restrict__ Xb,
               const unsigned short* __restrict__ P,
               const float* __restrict__ gamma,
               const float* __restrict__ beta,
               float* __restrict__ out)
{
    const int lane = threadIdx.x & 63;
    const int r = blockIdx.x * 4 + (threadIdx.x >> 6);   // one wave per row
    const int t = r & (T_DIM - 1);
    const float inv6 = 1.0f / 6.0f;

    float v[32];
    const uint4* xrow = (const uint4*)(Xb + (size_t)r * D_DIM);
#pragma unroll
    for (int c = 0; c < 4; ++c) {
        float f[8]; unpack8(xrow[c * 64 + lane], f);
#pragma unroll
        for (int jj = 0; jj < 8; ++jj) v[c * 8 + jj] = f[jj];
    }

    if (t > 0) {            // tmp_t = LN(x_t + P_{t-1}/6)
        const uint4* prow = (const uint4*)(P + (size_t)(r - 1) * D_DIM);
#pragma unroll
        for (int c = 0; c < 4; ++c) {
            float f[8]; unpack8(prow[c * 64 + lane], f);
#pragma unroll
            for (int jj = 0; jj < 8; ++jj) v[c * 8 + jj] += f[jj] * inv6;
        }
        ln_wave(v, gamma, beta, lane);
    }
    if (t < T_DIM - 1) {    // out_t = LN(tmp_t + P_{t+1}/6)
        const uint4* prow = (const uint4*)(P + (size_t)(r + 1) * D_DIM);
#pragma unroll
        for (int c = 0; c < 4; ++c) {
            float f[8]; unpack8(prow[c * 64 + lane], f);
#pragma unroll
            for (int jj = 0; jj < 8; ++jj) v[c * 8 + jj] += f[jj] * inv6;
        }
        ln_wave(v, gamma, beta, lane);
    }

    float4* orow = (float4*)(out + (size_t)r * D_DIM);
#pragma unroll
    for (int c = 0; c < 4; ++c) {
        const int e = (c * 64 + lane) * 2;
        orow[e]     = (float4){v[c*8+0], v[c*8+1], v[c*8+2], v[c*8+3]};
        orow[e + 1] = (float4){v[c*8+4], v[c*8+5], v[c*8+6], v[c*8+7]};
    }
}

extern "C" void kernel_launch(void* const* d_in, const int* in_sizes, int n_in,
                              void* d_out, int out_size, void* d_ws, size_t ws_size,
                              hipStream_t stream) {
    // inputs (setup_inputs order): x, W1, b1, W2, b2, Wp, bp, gamma, beta — W1/b1/W2/b2 dead.
    const float* x     = (const float*)d_in[0];
    const float* Wp    = (const float*)d_in[5];
    const float* bp    = (const float*)d_in[6];
    const float* gamma = (const float*)d_in[7];
    const float* beta  = (const float*)d_in[8];
    float* out = (float*)d_out;

    // workspace layout: Xb bf16 [64 MiB] | Wb bf16 [8 MiB] | P bf16 [64 MiB]
    unsigned short* Xb = (unsigned short*)d_ws;
    unsigned short* Wb = Xb + (size_t)M_DIM * K_DIM;
    unsigned short* P  = Wb + (size_t)N_DIM * K_DIM;

    const int nx4   = (M_DIM * K_DIM) / 4;            // 8388608
    const int ntot4 = nx4 + (N_DIM * K_DIM) / 4;      // + 1048576
    cast_f32_bf16<<<(ntot4 + 255) / 256, 256, 0, stream>>>(x, Xb, Wp, Wb, nx4, ntot4);

    gemm_bt<<<(M_DIM / 256) * (N_DIM / 256), 512, 0, stream>>>(Xb, Wb, bp, P);  // 512 WGs
    ln_kernel<<<M_DIM / 4, 256, 0, stream>>>(Xb, P, gamma, beta, out);
}